// Round 1
// baseline (207.484 us; speedup 1.0000x reference)
//
#include <hip/hip_runtime.h>
#include <hip/hip_bf16.h>
#include <cstdint>
#include <cstddef>

#define B_SZ 2
#define L_SEQ 2048
#define DM 1024
#define NH 16
#define HDIM 64
#define BL (B_SZ * L_SEQ)   // 4096 rows total
#define QKV_N (3 * DM)      // 3072

typedef __attribute__((ext_vector_type(4))) float f32x4;
typedef __attribute__((ext_vector_type(8))) short bf16x8;
typedef unsigned short u16;
typedef __attribute__((ext_vector_type(4))) unsigned short u16x4;

__device__ __forceinline__ float bf2f(u16 u) {
  union { unsigned int i; float f; } c; c.i = ((unsigned int)u) << 16; return c.f;
}
__device__ __forceinline__ u16 f2bf(float f) {
  union { float f; unsigned int i; } c; c.f = f;
  unsigned int r = c.i + 0x7fffu + ((c.i >> 16) & 1u);  // RNE
  return (u16)(r >> 16);
}

__device__ __forceinline__ void gload_lds16(const void* g, void* l) {
  __builtin_amdgcn_global_load_lds(
      (const __attribute__((address_space(1))) void*)g,
      (__attribute__((address_space(3))) void*)l, 16, 0, 0);
}

// ---------------- fp32 -> bf16 convert ----------------
__global__ __launch_bounds__(256) void cvt_f32_bf16(const float* __restrict__ in,
                                                    u16* __restrict__ out, int n4) {
  int i = blockIdx.x * blockDim.x + threadIdx.x;
  const int stride = gridDim.x * blockDim.x;
  for (; i < n4; i += stride) {
    float4 v = ((const float4*)in)[i];
    u16x4 o;
    o[0] = f2bf(v.x); o[1] = f2bf(v.y); o[2] = f2bf(v.z); o[3] = f2bf(v.w);
    ((u16x4*)out)[i] = o;
  }
}

// ---------------- GEMM: C[M,N] = A[M,K] * B[N,K]^T (bf16 in, fp32 acc) ----
// 128x128 tile, BK=32, 4 waves (2x2), each wave 64x64 (4x4 frags of 16x16x32).
// Staging: global_load_lds width 16, LDS linear [128][32] bf16; the 16B slot
// within each 64B row is pre-swizzled on the GLOBAL source (slot ^= (row>>1)&3)
// so fragment ds_read_b128 is ~2-way-conflict-free.
template <bool BF16_OUT>
__global__ __launch_bounds__(256) void gemm_bt(
    const u16* __restrict__ A, const u16* __restrict__ B,
    void* __restrict__ Cv, int M, int N, int K) {
  __shared__ u16 As[128 * 32];
  __shared__ u16 Bs[128 * 32];
  const int tid = threadIdx.x;
  const int lane = tid & 63, w = tid >> 6;
  const int lr = lane & 15, lg = lane >> 4;
  const int wr = w >> 1, wc = w & 1;
  const int bm = blockIdx.y * 128, bn = blockIdx.x * 128;

  f32x4 acc[4][4] = {};

  const int l4 = lane >> 2;                              // row within 16-row chunk
  const int csw = ((lane & 3) ^ ((lane >> 3) & 3)) * 8;  // pre-swizzled source col
  const size_t aoff0 = (size_t)(bm + (w * 2 + 0) * 16 + l4) * K + csw;
  const size_t aoff1 = (size_t)(bm + (w * 2 + 1) * 16 + l4) * K + csw;
  const size_t boff0 = (size_t)(bn + (w * 2 + 0) * 16 + l4) * K + csw;
  const size_t boff1 = (size_t)(bn + (w * 2 + 1) * 16 + l4) * K + csw;
  u16* As0 = As + (w * 2 + 0) * 512;  // wave-uniform LDS bases
  u16* As1 = As + (w * 2 + 1) * 512;
  u16* Bs0 = Bs + (w * 2 + 0) * 512;
  u16* Bs1 = Bs + (w * 2 + 1) * 512;
  const int sw_rd = (lr >> 1) & 3;

  for (int k0 = 0; k0 < K; k0 += 32) {
    gload_lds16(A + aoff0 + k0, As0);
    gload_lds16(A + aoff1 + k0, As1);
    gload_lds16(B + boff0 + k0, Bs0);
    gload_lds16(B + boff1 + k0, Bs1);
    __syncthreads();

    bf16x8 af[4], bfr[4];
#pragma unroll
    for (int mt = 0; mt < 4; ++mt) {
      const int row = wr * 64 + mt * 16 + lr;
      af[mt] = *(const bf16x8*)&As[row * 32 + ((lg ^ sw_rd) * 8)];
    }
#pragma unroll
    for (int nt = 0; nt < 4; ++nt) {
      const int row = wc * 64 + nt * 16 + lr;
      bfr[nt] = *(const bf16x8*)&Bs[row * 32 + ((lg ^ sw_rd) * 8)];
    }
#pragma unroll
    for (int mt = 0; mt < 4; ++mt)
#pragma unroll
      for (int nt = 0; nt < 4; ++nt)
        acc[mt][nt] = __builtin_amdgcn_mfma_f32_16x16x32_bf16(af[mt], bfr[nt],
                                                              acc[mt][nt], 0, 0, 0);
    __syncthreads();
  }

#pragma unroll
  for (int mt = 0; mt < 4; ++mt)
#pragma unroll
    for (int nt = 0; nt < 4; ++nt)
#pragma unroll
      for (int r = 0; r < 4; ++r) {
        const int row = bm + wr * 64 + mt * 16 + lg * 4 + r;
        const int col = bn + wc * 64 + nt * 16 + lr;
        if (BF16_OUT)
          ((u16*)Cv)[(size_t)row * N + col] = f2bf(acc[mt][nt][r]);
        else
          ((float*)Cv)[(size_t)row * N + col] = acc[mt][nt][r];
      }
}

// ---------------- fused causal flash attention ----------------
// grid: (L/64 q-tiles [reversed: heavy first], B*H). 256 threads = 4 waves;
// wave w owns q rows [qt*64 + w*16, +16). KVBLK=64.
// K_lds[key][d] and Vt_lds[d][key] XOR-swizzled; P transposed via per-wave LDS.
__global__ __launch_bounds__(256) void attn_fused(const u16* __restrict__ qkv,
                                                  u16* __restrict__ aout) {
  __shared__ u16 Kl[64 * 64];
  __shared__ u16 Vt[64 * 64];
  __shared__ u16 Pl[4][16 * 64];

  const int tid = threadIdx.x;
  const int lane = tid & 63, w = tid >> 6;
  const int lr = lane & 15, lg = lane >> 4;
  const int bh = blockIdx.y;
  const int b = bh >> 4, h = bh & 15;
  const int qt = (int)(gridDim.x - 1) - (int)blockIdx.x;  // heavy tiles first
  const int qbase = qt * 64;

  const u16* base = qkv + (size_t)b * L_SEQ * QKV_N;

  // Q fragments (A-operand layout), pre-scaled by 1/sqrt(64)=0.125 (exact in bf16)
  bf16x8 aq[2];
  {
    const int qrow = qbase + w * 16 + lr;
    const u16* qp = base + (size_t)qrow * QKV_N + h * HDIM + lg * 8;
#pragma unroll
    for (int ds = 0; ds < 2; ++ds) {
      bf16x8 t = *(const bf16x8*)(qp + ds * 32);
#pragma unroll
      for (int i = 0; i < 8; ++i)
        t[i] = (short)f2bf(bf2f((u16)t[i]) * 0.125f);
      aq[ds] = t;
    }
  }

  float mrow[4], lrow[4];
  f32x4 o[4] = {};
#pragma unroll
  for (int r = 0; r < 4; ++r) { mrow[r] = -1e30f; lrow[r] = 0.f; }

  const int qout = qbase + w * 16 + lg * 4;  // +r = this lane's output rows

  for (int t = 0; t <= qt; ++t) {
    __syncthreads();  // previous iter's LDS reads done before overwrite
    // ---- stage K tile: 64 keys x 64 d, slot ^= (row&7)
    {
      const int row = tid >> 2;
      const int s0 = (tid & 3) * 2;
      const u16* gp = base + (size_t)(t * 64 + row) * QKV_N + DM + h * HDIM;
      bf16x8 k0 = *(const bf16x8*)(gp + s0 * 8);
      bf16x8 k1 = *(const bf16x8*)(gp + s0 * 8 + 8);
      const int r7 = row & 7;
      *(bf16x8*)&Kl[row * 64 + ((s0 ^ r7) * 8)] = k0;
      *(bf16x8*)&Kl[row * 64 + (((s0 + 1) ^ r7) * 8)] = k1;
    }
    // ---- stage V transposed: Vt[d][key], slot ^= ((d>>1)&7)
    {
      const int d0 = (tid & 31) * 2;       // two d rows per thread
      const int kkb = (tid >> 5) * 8;      // 8 keys per thread
      const u16* gp = base + (size_t)(t * 64 + kkb) * QKV_N + 2 * DM + h * HDIM + d0;
      bf16x8 v0, v1;
#pragma unroll
      for (int j = 0; j < 8; ++j) {
        const unsigned int u = *(const unsigned int*)(gp + (size_t)j * QKV_N);
        v0[j] = (short)(u & 0xffffu);
        v1[j] = (short)(u >> 16);
      }
      const int sw = (((tid >> 5)) ^ ((d0 >> 1) & 7)) * 8;
      *(bf16x8*)&Vt[d0 * 64 + sw] = v0;
      *(bf16x8*)&Vt[(d0 + 1) * 64 + sw] = v1;
    }
    __syncthreads();

    // ---- S = (Q/8)·K^T : D-layout row q = lg*4+r, col k = lr (+16*kt)
    f32x4 s[4] = {};
#pragma unroll
    for (int ds = 0; ds < 2; ++ds)
#pragma unroll
      for (int kt = 0; kt < 4; ++kt) {
        const int krow = kt * 16 + lr;
        const bf16x8 bk =
            *(const bf16x8*)&Kl[krow * 64 + (((ds * 4 + lg) ^ (krow & 7)) * 8)];
        s[kt] = __builtin_amdgcn_mfma_f32_16x16x32_bf16(aq[ds], bk, s[kt], 0, 0, 0);
      }

    // ---- causal mask + online softmax (16-lane group shuffles)
    const int kb = t * 64 + lr;
#pragma unroll
    for (int kt = 0; kt < 4; ++kt) {
      const int k = kb + kt * 16;
#pragma unroll
      for (int r = 0; r < 4; ++r)
        if (k > qout + r) s[kt][r] = -1e30f;
    }
    float tmx[4];
#pragma unroll
    for (int r = 0; r < 4; ++r)
      tmx[r] = fmaxf(fmaxf(s[0][r], s[1][r]), fmaxf(s[2][r], s[3][r]));
#pragma unroll
    for (int off = 1; off < 16; off <<= 1)
#pragma unroll
      for (int r = 0; r < 4; ++r)
        tmx[r] = fmaxf(tmx[r], __shfl_xor(tmx[r], off));

    float alpha[4], rs[4];
#pragma unroll
    for (int r = 0; r < 4; ++r) {
      const float mnew = fmaxf(mrow[r], tmx[r]);
      alpha[r] = exp2f((mrow[r] - mnew) * 1.44269504f);
      mrow[r] = mnew;
      rs[r] = 0.f;
    }
#pragma unroll
    for (int kt = 0; kt < 4; ++kt)
#pragma unroll
      for (int r = 0; r < 4; ++r) {
        const float p = exp2f((s[kt][r] - mrow[r]) * 1.44269504f);
        s[kt][r] = p;
        rs[r] += p;
      }
#pragma unroll
    for (int off = 1; off < 16; off <<= 1)
#pragma unroll
      for (int r = 0; r < 4; ++r)
        rs[r] += __shfl_xor(rs[r], off);
#pragma unroll
    for (int r = 0; r < 4; ++r) lrow[r] = lrow[r] * alpha[r] + rs[r];
#pragma unroll
    for (int dt = 0; dt < 4; ++dt)
#pragma unroll
      for (int r = 0; r < 4; ++r) o[dt][r] *= alpha[r];

    // ---- P: D-layout -> A-layout via per-wave swizzled LDS
#pragma unroll
    for (int kt = 0; kt < 4; ++kt) {
      const int k = kt * 16 + lr;
#pragma unroll
      for (int r = 0; r < 4; ++r) {
        const int q = lg * 4 + r;
        Pl[w][q * 64 + (((k >> 3) ^ (q & 7)) * 8) + (k & 7)] = f2bf(s[kt][r]);
      }
    }
    // ---- PV: O[q][d] += P[q][k] * V[k][d]
#pragma unroll
    for (int ks = 0; ks < 2; ++ks) {
      const bf16x8 ap =
          *(const bf16x8*)&Pl[w][lr * 64 + (((ks * 4 + lg) ^ (lr & 7)) * 8)];
#pragma unroll
      for (int dt = 0; dt < 4; ++dt) {
        const int drow = dt * 16 + lr;
        const bf16x8 bv =
            *(const bf16x8*)&Vt[drow * 64 + (((ks * 4 + lg) ^ ((drow >> 1) & 7)) * 8)];
        o[dt] = __builtin_amdgcn_mfma_f32_16x16x32_bf16(ap, bv, o[dt], 0, 0, 0);
      }
    }
  }

  // ---- epilogue: O / l -> aout[b, q, h*64 + d] (bf16)
  float inv[4];
#pragma unroll
  for (int r = 0; r < 4; ++r) inv[r] = 1.f / lrow[r];
#pragma unroll
  for (int dt = 0; dt < 4; ++dt)
#pragma unroll
    for (int r = 0; r < 4; ++r) {
      const int q = qout + r;
      aout[(size_t)(b * L_SEQ + q) * DM + h * HDIM + dt * 16 + lr] =
          f2bf(o[dt][r] * inv[r]);
    }
}

// ---------------- host launch ----------------
extern "C" void kernel_launch(void* const* d_in, const int* in_sizes, int n_in,
                              void* d_out, int out_size, void* d_ws, size_t ws_size,
                              hipStream_t stream) {
  (void)in_sizes; (void)n_in; (void)out_size; (void)ws_size;
  const float* x = (const float*)d_in[0];     // [4096][1024]
  const float* wqkv = (const float*)d_in[1];  // [3072][1024]
  const float* wo = (const float*)d_in[2];    // [1024][1024]

  char* ws = (char*)d_ws;
  // layout (40 MB): x_bf 8MB | w_bf 6MB | wo_bf 2MB | qkv_bf 24MB
  // x_bf region is reused as attention output (x no longer needed then).
  u16* x_bf = (u16*)(ws);
  u16* w_bf = (u16*)(ws + (size_t)(8u << 20));
  u16* wo_bf = (u16*)(ws + (size_t)(14u << 20));
  u16* qkv_bf = (u16*)(ws + (size_t)(16u << 20));
  u16* ao_bf = x_bf;  // alias

  cvt_f32_bf16<<<2048, 256, 0, stream>>>(x, x_bf, BL * DM / 4);
  cvt_f32_bf16<<<2048, 256, 0, stream>>>(wqkv, w_bf, QKV_N * DM / 4);
  cvt_f32_bf16<<<1024, 256, 0, stream>>>(wo, wo_bf, DM * DM / 4);

  dim3 g1(QKV_N / 128, BL / 128);  // (24, 32)
  gemm_bt<true><<<g1, 256, 0, stream>>>(x_bf, w_bf, (void*)qkv_bf, BL, QKV_N, DM);

  dim3 g2(L_SEQ / 64, B_SZ * NH);  // (32, 32)
  attn_fused<<<g2, 256, 0, stream>>>(qkv_bf, ao_bf);

  dim3 g3(DM / 128, BL / 128);  // (8, 32)
  gemm_bt<false><<<g3, 256, 0, stream>>>(ao_bf, wo_bf, d_out, BL, DM, DM);
}